// Round 6
// baseline (39.074 us; speedup 1.0000x reference)
//
#include <hip/hip_runtime.h>

typedef _Float16 f16x8 __attribute__((ext_vector_type(8)));
typedef _Float16 f16x4 __attribute__((ext_vector_type(4)));
typedef __fp16 fp16x2 __attribute__((ext_vector_type(2)));
typedef float f32x4 __attribute__((ext_vector_type(4)));

#define IMG 512
#define NB 32
#define BCOL 64            /* out cols per block */
#define BROW 16            /* out rows per block */
#define GXT (IMG/BCOL)     /* 8  */
#define GYT (IMG/BROW)     /* 32 */
#define NBLK (GXT*GYT*NB)  /* 8192 */
#define ICOL 80            /* staged input cols (74 real + pad) */
#define INSTR 40           /* slot stride: 80B rows, 20 words -> 2-way (free) */
#define VSTR 88            /* lds_v row stride: 176B, 44 words -> 2-way (free) */
#define VOFF (16*VSTR)

// sigma=1.5, 11-tap normalized Gaussian (validated R1-R5, absmax 0.0)
#define GW_LIST { 0.0010283804f, 0.0075987583f, 0.0360007700f, 0.1093606900f, \
  0.2130055300f, 0.2660117200f, 0.2130055300f, 0.1093606900f, 0.0360007700f, \
  0.0075987583f, 0.0010283804f }

__global__ __launch_bounds__(256, 6) void ssim_mfma(const float* __restrict__ img1,
                                                    const float* __restrict__ img2,
                                                    float* __restrict__ partials) {
    // input, col-major per column (K=row-slots contiguous); slots 26..31 zero
    __shared__ _Float16 lds_in[2][ICOL][INSTR];
    // v-conv output V[row 0..15][col 0..79], row-major fp16
    __shared__ _Float16 lds_v[5*VOFF];
    __shared__ _Float16 gwt[64];
    __shared__ float red[4];

    const int tid  = threadIdx.x;
    const int lane = tid & 63;
    const int lm   = lane & 15;
    const int kg   = lane >> 4;
    const int w    = tid >> 6;

    const int bx = blockIdx.x, by = blockIdx.y, bz = blockIdx.z;
    const float* __restrict__ p1 = img1 + (size_t)bz * (IMG*IMG);
    const float* __restrict__ p2 = img2 + (size_t)bz * (IMG*IMG);
    const int x0 = bx * BCOL;
    const int y0 = by * BROW;

    // ---- staging: 80 cols x 2 slot-halves (16 slots each); rows y0-5..y0+20 ----
    {
        const int ci = tid & 127;
        const int hh = tid >> 7;
        if (ci < ICOL) {
            const int gc = x0 - 5 + ci;
            const bool okc = (gc >= 0) && (gc < IMG);
            const int gcc = okc ? gc : 0;
            union { _Float16 h[16]; f16x8 v[2]; } ua, ub;
            const int slot0 = hh * 16;
#pragma unroll
            for (int p = 0; p < 16; ++p) {
                const int slot = slot0 + p;
                const int ar = y0 - 5 + slot;
                const bool ok = okc & (slot < 26) & (ar >= 0) & (ar < IMG);
                const int arc = ok ? ar : 0;
                float v1 = p1[arc*IMG + gcc];
                float v2 = p2[arc*IMG + gcc];
                ua.h[p] = (_Float16)(ok ? v1 : 0.f);
                ub.h[p] = (_Float16)(ok ? v2 : 0.f);
            }
            *(f16x8*)&lds_in[0][ci][slot0]     = ua.v[0];
            *(f16x8*)&lds_in[0][ci][slot0 + 8] = ua.v[1];
            *(f16x8*)&lds_in[1][ci][slot0]     = ub.v[0];
            *(f16x8*)&lds_in[1][ci][slot0 + 8] = ub.v[1];
        }
    }
    // ---- gaussian band table ----
    if (tid < 64) {
        const float GWc[11] = GW_LIST;
        float wv = 0.f;
        const int t = tid - 16;
#pragma unroll
        for (int k = 0; k < 11; ++k) if (t == k) wv = GWc[k];
        gwt[tid] = (_Float16)wv;
    }
    __syncthreads();

    // banded weight fragment: B[k][n] = GW[k-n], serves BOTH conv stages
    union { _Float16 h[8]; f16x8 v; } wu;
#pragma unroll
    for (int i = 0; i < 8; ++i) wu.h[i] = gwt[16 + kg*8 + i - lm];

    const f32x4 zc = {0.f, 0.f, 0.f, 0.f};

    // stage V tile: A = X^T (b128 from col-major lds_in), B = weights.
    // lane(lm,kg) -> D[m=kg*4+j][n=lm] = V[row lm][col cb*16+kg*4+j] -> b64 store
    auto vtile = [&](int cb) {
        const f16x8 xf = *(const f16x8*)&lds_in[0][cb*16 + lm][kg*8];
        const f16x8 yf = *(const f16x8*)&lds_in[1][cb*16 + lm][kg*8];
        const f16x8 fr0 = xf, fr1 = yf;
        const f16x8 fr2 = xf*xf, fr3 = yf*yf, fr4 = xf*yf;
        const int cbase = cb*16 + kg*4;
#define DO_F(F, FR) { \
        const f32x4 d = __builtin_amdgcn_mfma_f32_16x16x32_f16(FR, wu.v, zc, 0, 0, 0); \
        union { fp16x2 p[2]; f16x4 v4; } pk; \
        pk.p[0] = __builtin_amdgcn_cvt_pkrtz(d[0], d[1]); \
        pk.p[1] = __builtin_amdgcn_cvt_pkrtz(d[2], d[3]); \
        *(f16x4*)&lds_v[(F)*VOFF + lm*VSTR + cbase] = pk.v4; }
        DO_F(0, fr0) DO_F(1, fr1) DO_F(2, fr2) DO_F(3, fr3) DO_F(4, fr4)
#undef DO_F
    };

    vtile(w);
    if (w == 0) vtile(4);   // 5th column tile (halo cols 64..79)
    __syncthreads();

    // stage H: A = V rows (b128, k=cols contiguous), B = weights; + SSIM map
    float local = 0.f;
    {
        const int cb2 = w*16 + kg*8;
        const f16x8 a0 = *(const f16x8*)&lds_v[0*VOFF + lm*VSTR + cb2];
        const f16x8 a1 = *(const f16x8*)&lds_v[1*VOFF + lm*VSTR + cb2];
        const f16x8 a2 = *(const f16x8*)&lds_v[2*VOFF + lm*VSTR + cb2];
        const f16x8 a3 = *(const f16x8*)&lds_v[3*VOFF + lm*VSTR + cb2];
        const f16x8 a4 = *(const f16x8*)&lds_v[4*VOFF + lm*VSTR + cb2];
        const f32x4 d0 = __builtin_amdgcn_mfma_f32_16x16x32_f16(a0, wu.v, zc, 0,0,0);
        const f32x4 d1 = __builtin_amdgcn_mfma_f32_16x16x32_f16(a1, wu.v, zc, 0,0,0);
        const f32x4 d2 = __builtin_amdgcn_mfma_f32_16x16x32_f16(a2, wu.v, zc, 0,0,0);
        const f32x4 d3 = __builtin_amdgcn_mfma_f32_16x16x32_f16(a3, wu.v, zc, 0,0,0);
        const f32x4 d4 = __builtin_amdgcn_mfma_f32_16x16x32_f16(a4, wu.v, zc, 0,0,0);
#pragma unroll
        for (int j = 0; j < 4; ++j) {
            const float mu1 = d0[j], mu2 = d1[j];
            const float m11 = mu1*mu1, m22 = mu2*mu2, m12 = mu1*mu2;
            const float s1 = d2[j] - m11, s2 = d3[j] - m22, sx = d4[j] - m12;
            const float num = (2.f*m12 + 1e-4f) * (2.f*sx + 9e-4f);
            const float den = (m11 + m22 + 1e-4f) * (s1 + s2 + 9e-4f);
            local += num * __builtin_amdgcn_rcpf(den);
        }
    }

    // ---- block reduction ----
#pragma unroll
    for (int off = 32; off > 0; off >>= 1)
        local += __shfl_down(local, off, 64);
    if (lane == 0) red[w] = local;
    __syncthreads();
    if (tid == 0) {
        partials[(size_t)((bz*GYT + by)*GXT + bx)] = red[0] + red[1] + red[2] + red[3];
    }
}

__global__ __launch_bounds__(256) void ssim_finalize(const float* __restrict__ partials,
                                                     int n, float* __restrict__ out) {
    __shared__ double red[4];
    double s = 0.0;
    for (int i = threadIdx.x; i < n; i += 256) s += (double)partials[i];
#pragma unroll
    for (int off = 32; off > 0; off >>= 1)
        s += __shfl_down(s, off, 64);
    if ((threadIdx.x & 63) == 0) red[threadIdx.x >> 6] = s;
    __syncthreads();
    if (threadIdx.x == 0) {
        double tot = red[0] + red[1] + red[2] + red[3];
        out[0] = (float)(1.0 - tot / (32.0 * 512.0 * 512.0));
    }
}

extern "C" void kernel_launch(void* const* d_in, const int* in_sizes, int n_in,
                              void* d_out, int out_size, void* d_ws, size_t ws_size,
                              hipStream_t stream) {
    const float* img1 = (const float*)d_in[0];
    const float* img2 = (const float*)d_in[1];
    float* out = (float*)d_out;
    float* partials = (float*)d_ws;

    dim3 grid(GXT, GYT, NB);   // 8 x 32 x 32 = 8192 blocks
    ssim_mfma<<<grid, 256, 0, stream>>>(img1, img2, partials);
    ssim_finalize<<<1, 256, 0, stream>>>(partials, NBLK, out);
}